// Round 1
// baseline (677.221 us; speedup 1.0000x reference)
//
#include <hip/hip_runtime.h>

#define NBINS 100
#define NSUB  16   // LDS sub-histogram copies; lane -> copy (tid & 15)

// ---------------------------------------------------------------------------
// Kernel 1: zero the global bin accumulator in d_ws (ws is poisoned 0xAA once
// and never re-poisoned, so we must zero it ourselves every call).
// ---------------------------------------------------------------------------
__global__ void histo_zero(float* __restrict__ g) {
    int i = threadIdx.x;
    if (i < NBINS) g[i] = 0.0f;
}

// ---------------------------------------------------------------------------
// Kernel 2: single streaming pass. Each x contributes w0=r*(1-t) to bin k and
// w1=r*t to bin k+1 where k=floor(100x), t=frac(100x), r=0.01. Accumulate in
// 16 LDS sub-histograms (fp32 ds_add), reduce to per-block partial, one global
// fp32 atomic per bin per block.
// ---------------------------------------------------------------------------
__global__ __launch_bounds__(256) void histo_accum(const float* __restrict__ x,
                                                   float* __restrict__ gbins,
                                                   int n4, int n) {
    __shared__ float h[NSUB * NBINS];
    const int tid = threadIdx.x;

    for (int i = tid; i < NSUB * NBINS; i += blockDim.x) h[i] = 0.0f;
    __syncthreads();

    float* hs = &h[(tid & (NSUB - 1)) * NBINS];

    const float4* __restrict__ x4 = (const float4*)x;
    const int stride = gridDim.x * blockDim.x;

    for (int i = blockIdx.x * blockDim.x + tid; i < n4; i += stride) {
        float4 v = x4[i];
        float vv[4] = {v.x, v.y, v.z, v.w};
#pragma unroll
        for (int j = 0; j < 4; ++j) {
            float xf = vv[j] * 100.0f;          // in [0, 100)
            float fk = floorf(xf);
            int   k  = (int)fk;
            k = min(max(k, 0), NBINS - 1);      // safety clamp
            float w1 = (xf - fk) * 0.01f;       // r * t
            float w0 = 0.01f - w1;              // r * (1 - t)
            unsafeAtomicAdd(&hs[k], w0);
            if (k < NBINS - 1) unsafeAtomicAdd(&hs[k + 1], w1);
        }
    }

    // scalar tail (n not multiple of 4) — handled by block 0 only
    if (blockIdx.x == 0) {
        for (int i = n4 * 4 + tid; i < n; i += blockDim.x) {
            float xf = x[i] * 100.0f;
            float fk = floorf(xf);
            int   k  = (int)fk;
            k = min(max(k, 0), NBINS - 1);
            float w1 = (xf - fk) * 0.01f;
            float w0 = 0.01f - w1;
            unsafeAtomicAdd(&hs[k], w0);
            if (k < NBINS - 1) unsafeAtomicAdd(&hs[k + 1], w1);
        }
    }

    __syncthreads();

    // reduce NSUB copies -> one partial per bin, one global atomic per bin
    for (int b = tid; b < NBINS; b += blockDim.x) {
        float s = 0.0f;
#pragma unroll
        for (int c = 0; c < NSUB; ++c) s += h[c * NBINS + b];
        unsafeAtomicAdd(&gbins[b], s);
    }
}

// ---------------------------------------------------------------------------
// Kernel 3: normalize — out[i] = g[i] / (sum(g) + 1e-6). One block, 128 thr.
// ---------------------------------------------------------------------------
__global__ void histo_final(const float* __restrict__ g, float* __restrict__ out) {
    __shared__ float wsum[2];
    const int t = threadIdx.x;           // 128 threads = 2 waves
    float v = (t < NBINS) ? g[t] : 0.0f;

    float s = v;
#pragma unroll
    for (int o = 32; o > 0; o >>= 1) s += __shfl_down(s, o, 64);
    if ((t & 63) == 0) wsum[t >> 6] = s;
    __syncthreads();

    float total = wsum[0] + wsum[1];
    if (t < NBINS) out[t] = v / (total + 1e-6f);
}

extern "C" void kernel_launch(void* const* d_in, const int* in_sizes, int n_in,
                              void* d_out, int out_size, void* d_ws, size_t ws_size,
                              hipStream_t stream) {
    const float* x   = (const float*)d_in[0];  // [64 * 1048576] fp32 in [0,1)
    float*       out = (float*)d_out;          // [100] fp32
    float*       g   = (float*)d_ws;           // 100-float accumulator

    const int n  = in_sizes[0];
    const int n4 = n / 4;

    histo_zero<<<1, 128, 0, stream>>>(g);

    const int block  = 256;
    int blocks = (n4 + block - 1) / block;
    if (blocks > 2048) blocks = 2048;          // grid-stride the rest
    histo_accum<<<blocks, block, 0, stream>>>(x, g, n4, n);

    histo_final<<<1, 128, 0, stream>>>(g, out);
}